// Round 1
// baseline (8013.678 us; speedup 1.0000x reference)
//
#include <hip/hip_runtime.h>

#define TPB 256
#define EPSV 1e-5f

__device__ __forceinline__ float sigm(float x){ return 1.0f/(1.0f + __expf(-x)); }

// ---------------- K1: fused node GEMMs: xt=Ax+bA, Bx, Dx, Ex ----------------
// grid (ceil(N/256), 4); lane-per-row, W broadcast from LDS (wave-uniform reads).
__global__ __launch_bounds__(TPB) void k_node_gemm(
    const float* __restrict__ x,
    const float* __restrict__ WA, const float* __restrict__ WB,
    const float* __restrict__ WD, const float* __restrict__ WE,
    const float* __restrict__ bA, const float* __restrict__ bB,
    const float* __restrict__ bD, const float* __restrict__ bE,
    float* __restrict__ oA, float* __restrict__ oB,
    float* __restrict__ oD, float* __restrict__ oE, int N)
{
    __shared__ float Wl[4096];
    __shared__ float bl[64];
    const int tid = threadIdx.x;
    const int m = blockIdx.y;
    const float* W = (m==0)?WA:(m==1)?WB:(m==2)?WD:WE;
    const float* b = (m==0)?bA:(m==1)?bB:(m==2)?bD:bE;
    float* o       = (m==0)?oA:(m==1)?oB:(m==2)?oD:oE;
    {
        const float4* Wg=(const float4*)W; float4* Wd=(float4*)Wl;
        #pragma unroll
        for (int i=0;i<4;i++) Wd[tid + i*TPB] = Wg[tid + i*TPB];
        if (tid<64) bl[tid]=b[tid];
    }
    __syncthreads();
    const int r = blockIdx.x*TPB + tid;
    if (r >= N) return;
    float xr[64];
    {
        const float4* x4=(const float4*)x + (size_t)r*16;
        #pragma unroll
        for (int i=0;i<16;i++){ float4 t=x4[i]; xr[i*4]=t.x; xr[i*4+1]=t.y; xr[i*4+2]=t.z; xr[i*4+3]=t.w; }
    }
    float4* o4=(float4*)o + (size_t)r*16;
    const float4* Wl4=(const float4*)Wl;
    for (int jc=0;jc<8;jc++){
        float acc[8];
        #pragma unroll
        for (int jj=0;jj<8;jj++) acc[jj]=bl[jc*8+jj];
        #pragma unroll
        for (int kc=0;kc<16;kc++){
            #pragma unroll
            for (int jj=0;jj<8;jj++){
                float4 w=Wl4[(jc*8+jj)*16+kc];
                acc[jj]=fmaf(xr[kc*4],w.x,fmaf(xr[kc*4+1],w.y,fmaf(xr[kc*4+2],w.z,fmaf(xr[kc*4+3],w.w,acc[jj]))));
            }
        }
        float4 q0={acc[0],acc[1],acc[2],acc[3]};
        float4 q1={acc[4],acc[5],acc[6],acc[7]};
        o4[jc*2]=q0; o4[jc*2+1]=q1;
    }
}

// ---------------- K2: per-edge Ce GEMM + gather + gate + scatter-add + e-stats ----------------
__global__ __launch_bounds__(TPB) void k_edge(
    const float* __restrict__ ea, const int* __restrict__ ei,
    const float* __restrict__ WC, const float* __restrict__ bC,
    const float* __restrict__ Bx, const float* __restrict__ Dx, const float* __restrict__ Ex,
    float* __restrict__ eij, float* __restrict__ xt, float* __restrict__ est,
    int E, int N)
{
    __shared__ float Wl[4096];
    __shared__ float bl[64];
    const int tid=threadIdx.x;
    {
        const float4* Wg=(const float4*)WC; float4* Wd=(float4*)Wl;
        #pragma unroll
        for (int i=0;i<4;i++) Wd[tid+i*TPB]=Wg[tid+i*TPB];
        if (tid<64) bl[tid]=bC[tid];
    }
    __syncthreads();
    const int e = blockIdx.x*TPB+tid;
    const bool act = e<E;
    const int ec = act? e:0;
    const int row = ei[ec];
    const int col = ei[E+ec];
    float xr[64];
    {
        const float4* a4=(const float4*)ea + (size_t)ec*16;
        #pragma unroll
        for (int i=0;i<16;i++){ float4 t=a4[i]; xr[i*4]=t.x; xr[i*4+1]=t.y; xr[i*4+2]=t.z; xr[i*4+3]=t.w; }
    }
    const float4* B4=(const float4*)Bx + (size_t)col*16;
    const float4* D4=(const float4*)Dx + (size_t)row*16;
    const float4* F4=(const float4*)Ex + (size_t)col*16;
    float4* o4=(float4*)eij + (size_t)ec*16;
    float* xtr = xt + (size_t)row*64;
    const float4* Wl4=(const float4*)Wl;
    for (int jc=0;jc<8;jc++){
        float acc[8];
        #pragma unroll
        for (int jj=0;jj<8;jj++) acc[jj]=bl[jc*8+jj];
        #pragma unroll
        for (int kc=0;kc<16;kc++){
            #pragma unroll
            for (int jj=0;jj<8;jj++){
                float4 w=Wl4[(jc*8+jj)*16+kc];
                acc[jj]=fmaf(xr[kc*4],w.x,fmaf(xr[kc*4+1],w.y,fmaf(xr[kc*4+2],w.z,fmaf(xr[kc*4+3],w.w,acc[jj]))));
            }
        }
        float4 d0=D4[jc*2], d1=D4[jc*2+1];
        float4 f0=F4[jc*2], f1=F4[jc*2+1];
        float4 g0=B4[jc*2], g1=B4[jc*2+1];
        float v[8];
        v[0]=acc[0]+d0.x+f0.x; v[1]=acc[1]+d0.y+f0.y;
        v[2]=acc[2]+d0.z+f0.z; v[3]=acc[3]+d0.w+f0.w;
        v[4]=acc[4]+d1.x+f1.x; v[5]=acc[5]+d1.y+f1.y;
        v[6]=acc[6]+d1.z+f1.z; v[7]=acc[7]+d1.w+f1.w;
        if (act){
            float4 q0={v[0],v[1],v[2],v[3]}, q1={v[4],v[5],v[6],v[7]};
            o4[jc*2]=q0; o4[jc*2+1]=q1;
            float bb[8]={g0.x,g0.y,g0.z,g0.w,g1.x,g1.y,g1.z,g1.w};
            #pragma unroll
            for (int jj=0;jj<8;jj++){
                float msg = bb[jj]*sigm(v[jj]);
                unsafeAtomicAdd(&xtr[jc*8+jj], msg);
            }
        }
        // e_ij column stats (sum, sumsq) — full-wave butterfly, lane0 fire-and-forget atomics
        float s[8], q[8];
        #pragma unroll
        for (int jj=0;jj<8;jj++){ float vv = act? v[jj]:0.0f; s[jj]=vv; q[jj]=vv*vv; }
        #pragma unroll
        for (int off=1; off<64; off<<=1){
            #pragma unroll
            for (int jj=0;jj<8;jj++){
                s[jj] += __shfl_xor(s[jj], off, 64);
                q[jj] += __shfl_xor(q[jj], off, 64);
            }
        }
        if ((tid&63)==0){
            #pragma unroll
            for (int jj=0;jj<8;jj++){
                unsafeAtomicAdd(&est[jc*8+jj], s[jj]);
                unsafeAtomicAdd(&est[64+jc*8+jj], q[jj]);
            }
        }
    }
}

// ---------------- column stats of an [N,64] array -> sums[0:64]=sum, [64:128]=sumsq ----------------
__global__ __launch_bounds__(TPB) void k_colstats(
    const float* __restrict__ src, float* __restrict__ sums, int N)
{
    __shared__ float ls[TPB], lq[TPB];
    const int tid=threadIdx.x;
    const int j = tid&63, rg = tid>>6;
    float s=0.f, q=0.f;
    for (int r = blockIdx.x*4+rg; r<N; r += gridDim.x*4){
        float v = src[(size_t)r*64+j];
        s+=v; q+=v*v;
    }
    ls[tid]=s; lq[tid]=q;
    __syncthreads();
    if (tid<64){
        s=ls[tid]+ls[tid+64]+ls[tid+128]+ls[tid+192];
        q=lq[tid]+lq[tid+64]+lq[tid+128]+lq[tid+192];
        unsafeAtomicAdd(&sums[tid], s);
        unsafeAtomicAdd(&sums[64+tid], q);
    }
}

// ---------------- K4: xf = x + relu(bn(xt)); accumulates xf stats ----------------
__global__ __launch_bounds__(TPB) void k_xupdate(
    const float* __restrict__ x, const float* __restrict__ xt,
    const float* __restrict__ stin, const float* __restrict__ gx, const float* __restrict__ bx,
    float* __restrict__ xf, float* __restrict__ stout, int N)
{
    __shared__ float m_[64], r_[64], gl[64], bl[64], ss[64], sq[64];
    const int tid=threadIdx.x;
    if (tid<64){
        float mm=stin[tid]/(float)N;
        float vv=stin[64+tid]/(float)N - mm*mm;
        m_[tid]=mm; r_[tid]=rsqrtf(vv+EPSV);
        gl[tid]=gx[tid]; bl[tid]=bx[tid];
        ss[tid]=0.f; sq[tid]=0.f;
    }
    __syncthreads();
    const int i4 = blockIdx.x*TPB+tid;
    if (i4 < N*16){
        const int jg = i4&15;
        float a[4]; *(float4*)a = ((const float4*)x)[i4];
        float t[4]; *(float4*)t = ((const float4*)xt)[i4];
        float o[4];
        #pragma unroll
        for (int c=0;c<4;c++){
            int j=jg*4+c;
            float xn = gl[j]*((t[c]-m_[j])*r_[j]) + bl[j];
            xn = fmaxf(xn, 0.f);
            o[c]=a[c]+xn;
            unsafeAtomicAdd(&ss[j], o[c]);
            unsafeAtomicAdd(&sq[j], o[c]*o[c]);
        }
        ((float4*)xf)[i4] = *(float4*)o;
    }
    __syncthreads();
    if (tid<64){
        unsafeAtomicAdd(&stout[tid], ss[tid]);
        unsafeAtomicAdd(&stout[64+tid], sq[tid]);
    }
}

// ---------------- K5: h1 = relu(bn1(xf) @ W1.T + b1), half of 128 outputs per block.y ----------------
__global__ __launch_bounds__(TPB) void k_ffn1(
    const float* __restrict__ xf, const float* __restrict__ stxf,
    const float* __restrict__ g1, const float* __restrict__ b1n,
    const float* __restrict__ W1, const float* __restrict__ b1,
    float* __restrict__ h1, int N)
{
    __shared__ float Wl[4096];
    __shared__ float m_[64], r_[64], gl[64], bl[64], bj[64];
    const int tid=threadIdx.x;
    const int half=blockIdx.y;
    {
        const float4* Wg=(const float4*)(W1 + (size_t)half*4096);
        float4* Wd=(float4*)Wl;
        #pragma unroll
        for (int i=0;i<4;i++) Wd[tid+i*TPB]=Wg[tid+i*TPB];
        if (tid<64){
            float mm=stxf[tid]/(float)N;
            float vv=stxf[64+tid]/(float)N - mm*mm;
            m_[tid]=mm; r_[tid]=rsqrtf(vv+EPSV);
            gl[tid]=g1[tid]; bl[tid]=b1n[tid];
            bj[tid]=b1[half*64+tid];
        }
    }
    __syncthreads();
    const int r = blockIdx.x*TPB+tid;
    if (r>=N) return;
    float xn[64];
    {
        const float4* x4=(const float4*)xf + (size_t)r*16;
        #pragma unroll
        for (int i=0;i<16;i++){
            float t[4]; *(float4*)t = x4[i];
            #pragma unroll
            for (int c=0;c<4;c++){
                int k=i*4+c;
                xn[k] = gl[k]*((t[c]-m_[k])*r_[k]) + bl[k];
            }
        }
    }
    float4* o4=(float4*)h1 + (size_t)r*32 + half*16;
    const float4* Wl4=(const float4*)Wl;
    for (int jc=0;jc<8;jc++){
        float acc[8];
        #pragma unroll
        for (int jj=0;jj<8;jj++) acc[jj]=bj[jc*8+jj];
        #pragma unroll
        for (int kc=0;kc<16;kc++){
            #pragma unroll
            for (int jj=0;jj<8;jj++){
                float4 w=Wl4[(jc*8+jj)*16+kc];
                acc[jj]=fmaf(xn[kc*4],w.x,fmaf(xn[kc*4+1],w.y,fmaf(xn[kc*4+2],w.z,fmaf(xn[kc*4+3],w.w,acc[jj]))));
            }
        }
        #pragma unroll
        for (int jj=0;jj<8;jj++) acc[jj]=fmaxf(acc[jj],0.f);
        float4 q0={acc[0],acc[1],acc[2],acc[3]};
        float4 q1={acc[4],acc[5],acc[6],acc[7]};
        o4[jc*2]=q0; o4[jc*2+1]=q1;
    }
}

// ---------------- K6: y = xf + (h1 @ W2.T + b2), 32 outputs per block.y half ----------------
__global__ __launch_bounds__(TPB) void k_ffn2(
    const float* __restrict__ h1, const float* __restrict__ xf,
    const float* __restrict__ W2, const float* __restrict__ b2,
    float* __restrict__ y, int N)
{
    __shared__ float Wl[4096];
    __shared__ float bj[32];
    const int tid=threadIdx.x;
    const int half=blockIdx.y;
    {
        const float4* Wg=(const float4*)(W2 + (size_t)half*32*128);
        float4* Wd=(float4*)Wl;
        #pragma unroll
        for (int i=0;i<4;i++) Wd[tid+i*TPB]=Wg[tid+i*TPB];
        if (tid<32) bj[tid]=b2[half*32+tid];
    }
    __syncthreads();
    const int r=blockIdx.x*TPB+tid;
    if (r>=N) return;
    float acc[32];
    #pragma unroll
    for (int j=0;j<32;j++) acc[j]=bj[j];
    const float4* hr=(const float4*)h1 + (size_t)r*32;
    const float4* Wl4=(const float4*)Wl;
    #pragma unroll 4
    for (int kc=0;kc<32;kc++){
        float t[4]; *(float4*)t = hr[kc];
        #pragma unroll
        for (int j=0;j<32;j++){
            float4 w=Wl4[j*32+kc];
            acc[j]=fmaf(t[0],w.x,fmaf(t[1],w.y,fmaf(t[2],w.z,fmaf(t[3],w.w,acc[j]))));
        }
    }
    const float4* xr4=(const float4*)xf + (size_t)r*16 + half*8;
    float4* y4=(float4*)y + (size_t)r*16 + half*8;
    #pragma unroll
    for (int jc=0;jc<8;jc++){
        float t[4]; *(float4*)t = xr4[jc];
        float o[4];
        o[0]=t[0]+acc[jc*4];   o[1]=t[1]+acc[jc*4+1];
        o[2]=t[2]+acc[jc*4+2]; o[3]=t[3]+acc[jc*4+3];
        y4[jc] = *(float4*)o;
    }
}

// ---------------- K7: out_x = bn2(y) ----------------
__global__ __launch_bounds__(TPB) void k_bnout(
    const float* __restrict__ y, const float* __restrict__ sty,
    const float* __restrict__ g2, const float* __restrict__ b2n,
    float* __restrict__ outx, int N)
{
    __shared__ float m_[64], r_[64], gl[64], bl[64];
    const int tid=threadIdx.x;
    if (tid<64){
        float mm=sty[tid]/(float)N;
        float vv=sty[64+tid]/(float)N - mm*mm;
        m_[tid]=mm; r_[tid]=rsqrtf(vv+EPSV);
        gl[tid]=g2[tid]; bl[tid]=b2n[tid];
    }
    __syncthreads();
    const int i4=blockIdx.x*TPB+tid;
    if (i4 >= N*16) return;
    const int jg=i4&15;
    float t[4]; *(float4*)t = ((const float4*)y)[i4];
    float o[4];
    #pragma unroll
    for (int c=0;c<4;c++){
        int j=jg*4+c;
        o[c] = gl[j]*((t[c]-m_[j])*r_[j]) + bl[j];
    }
    ((float4*)outx)[i4] = *(float4*)o;
}

// ---------------- K8: e_final = edge_attr + relu(bn_e(e_ij)) in-place in d_out ----------------
__global__ __launch_bounds__(TPB) void k_efinal(
    const float* __restrict__ ea, float* __restrict__ eio,
    const float* __restrict__ ste, const float* __restrict__ ge, const float* __restrict__ be,
    int E)
{
    __shared__ float m_[64], r_[64], gl[64], bl[64];
    const int tid=threadIdx.x;
    if (tid<64){
        float mm=ste[tid]/(float)E;
        float vv=ste[64+tid]/(float)E - mm*mm;
        m_[tid]=mm; r_[tid]=rsqrtf(vv+EPSV);
        gl[tid]=ge[tid]; bl[tid]=be[tid];
    }
    __syncthreads();
    const long i4=(long)blockIdx.x*TPB+tid;
    if (i4 >= (long)E*16) return;
    const int jg=(int)(i4&15);
    float t[4]; *(float4*)t = ((float4*)eio)[i4];
    float a[4]; *(float4*)a = ((const float4*)ea)[i4];
    float o[4];
    #pragma unroll
    for (int c=0;c<4;c++){
        int j=jg*4+c;
        float xn = gl[j]*((t[c]-m_[j])*r_[j]) + bl[j];
        o[c]=a[c]+fmaxf(xn,0.f);
    }
    ((float4*)eio)[i4] = *(float4*)o;
}

extern "C" void kernel_launch(void* const* d_in, const int* in_sizes, int n_in,
                              void* d_out, int out_size, void* d_ws, size_t ws_size,
                              hipStream_t stream)
{
    const float* x   = (const float*)d_in[0];
    const int*   ei  = (const int*)  d_in[1];
    const float* ea  = (const float*)d_in[2];
    const float* WA  = (const float*)d_in[3];  const float* bA  = (const float*)d_in[4];
    const float* WB  = (const float*)d_in[5];  const float* bB  = (const float*)d_in[6];
    const float* WC  = (const float*)d_in[7];  const float* bC  = (const float*)d_in[8];
    const float* WD  = (const float*)d_in[9];  const float* bD  = (const float*)d_in[10];
    const float* WE  = (const float*)d_in[11]; const float* bE  = (const float*)d_in[12];
    const float* g_x = (const float*)d_in[13]; const float* b_x = (const float*)d_in[14];
    const float* g_e = (const float*)d_in[15]; const float* b_e = (const float*)d_in[16];
    const float* g_n1= (const float*)d_in[17]; const float* b_n1= (const float*)d_in[18];
    const float* W1  = (const float*)d_in[19]; const float* b1  = (const float*)d_in[20];
    const float* W2  = (const float*)d_in[21]; const float* b2  = (const float*)d_in[22];
    const float* g_n2= (const float*)d_in[23]; const float* b_n2= (const float*)d_in[24];

    const int N = in_sizes[0]/64;
    const int E = in_sizes[2]/64;

    float* ws = (float*)d_ws;
    float* xt = ws;                          // [N,64]  Ax + aggr
    float* Bx = xt + (size_t)N*64;           // [N,64]
    float* Dx = Bx + (size_t)N*64;           // [N,64]
    float* Ex = Dx + (size_t)N*64;           // [N,64]
    float* xf = Ex + (size_t)N*64;           // [N,64]  x_final (pre-FFN-BN)
    float* yv = xf + (size_t)N*64;           // [N,64]  xf + h
    float* h1 = yv + (size_t)N*64;           // [N,128]
    float* st = h1 + (size_t)N*128;          // 512 floats of stats
    // st: [0:128) e_ij stats | [128:256) xt stats | [256:384) xf stats | [384:512) y stats

    float* outx = (float*)d_out;             // [N,64]  x_final output
    float* eij  = outx + (size_t)N*64;       // [E,64]  e_ij, then e_final in-place

    hipMemsetAsync(st, 0, 512*sizeof(float), stream);

    const int nbN   = (N+TPB-1)/TPB;
    const int nbE   = (E+TPB-1)/TPB;
    const int nbN16 = (N*16+TPB-1)/TPB;
    const long e16  = (long)E*16;
    const int nbE16 = (int)((e16+TPB-1)/TPB);

    k_node_gemm<<<dim3(nbN,4), TPB, 0, stream>>>(x,WA,WB,WD,WE,bA,bB,bD,bE,xt,Bx,Dx,Ex,N);
    k_edge     <<<nbE,          TPB, 0, stream>>>(ea,ei,WC,bC,Bx,Dx,Ex,eij,xt,st,E,N);
    k_colstats <<<256,          TPB, 0, stream>>>(xt, st+128, N);
    k_xupdate  <<<nbN16,        TPB, 0, stream>>>(x,xt,st+128,g_x,b_x,xf,st+256,N);
    k_ffn1     <<<dim3(nbN,2),  TPB, 0, stream>>>(xf,st+256,g_n1,b_n1,W1,b1,h1,N);
    k_ffn2     <<<dim3(nbN,2),  TPB, 0, stream>>>(h1,xf,W2,b2,yv,N);
    k_colstats <<<256,          TPB, 0, stream>>>(yv, st+384, N);
    k_bnout    <<<nbN16,        TPB, 0, stream>>>(yv,st+384,g_n2,b_n2,outx,N);
    k_efinal   <<<nbE16,        TPB, 0, stream>>>(ea,eij,st,g_e,b_e,E);
}

// Round 2
// 1903.203 us; speedup vs baseline: 4.2106x; 4.2106x over previous
//
#include <hip/hip_runtime.h>

#define TPB 256
#define EPSV 1e-5f

__device__ __forceinline__ float sigm(float x){ return 1.0f/(1.0f + __expf(-x)); }

// ---------------- generic row GEMM: out[r] = src[r] @ W.T + b (64x64) ----------------
// lane-per-row; W broadcast from LDS (wave-uniform reads = free broadcast).
__global__ __launch_bounds__(TPB) void k_rowgemm(
    const float* __restrict__ src, const float* __restrict__ W, const float* __restrict__ b,
    float* __restrict__ out, int rows)
{
    __shared__ float Wl[4096];
    __shared__ float bl[64];
    const int tid = threadIdx.x;
    {
        const float4* Wg=(const float4*)W; float4* Wd=(float4*)Wl;
        #pragma unroll
        for (int i=0;i<4;i++) Wd[tid + i*TPB] = Wg[tid + i*TPB];
        if (tid<64) bl[tid]=b[tid];
    }
    __syncthreads();
    const int r = blockIdx.x*TPB + tid;
    if (r >= rows) return;
    float xr[64];
    {
        const float4* x4=(const float4*)src + (size_t)r*16;
        #pragma unroll
        for (int i=0;i<16;i++){ float4 t=x4[i]; xr[i*4]=t.x; xr[i*4+1]=t.y; xr[i*4+2]=t.z; xr[i*4+3]=t.w; }
    }
    float4* o4=(float4*)out + (size_t)r*16;
    const float4* Wl4=(const float4*)Wl;
    for (int jc=0;jc<8;jc++){
        float acc[8];
        #pragma unroll
        for (int jj=0;jj<8;jj++) acc[jj]=bl[jc*8+jj];
        #pragma unroll
        for (int kc=0;kc<16;kc++){
            #pragma unroll
            for (int jj=0;jj<8;jj++){
                float4 w=Wl4[(jc*8+jj)*16+kc];
                acc[jj]=fmaf(xr[kc*4],w.x,fmaf(xr[kc*4+1],w.y,fmaf(xr[kc*4+2],w.z,fmaf(xr[kc*4+3],w.w,acc[jj]))));
            }
        }
        float4 q0={acc[0],acc[1],acc[2],acc[3]};
        float4 q1={acc[4],acc[5],acc[6],acc[7]};
        o4[jc*2]=q0; o4[jc*2+1]=q1;
    }
}

// ---------------- CSR build ----------------
__global__ __launch_bounds__(TPB) void k_hist(const int* __restrict__ ei, int* __restrict__ deg, int E){
    for (int e = blockIdx.x*TPB + threadIdx.x; e < E; e += gridDim.x*TPB)
        atomicAdd(&deg[ei[e]], 1);
}

__global__ __launch_bounds__(TPB) void k_scanA(const int* __restrict__ deg, int* __restrict__ rowptr,
                                               int* __restrict__ bsum, int N){
    __shared__ int sd[TPB];
    const int t = threadIdx.x; const int i = blockIdx.x*TPB + t;
    int v = (i<N)? deg[i] : 0;
    sd[t]=v; __syncthreads();
    for (int off=1; off<TPB; off<<=1){
        int x = (t>=off)? sd[t-off] : 0; __syncthreads();
        sd[t] += x; __syncthreads();
    }
    if (i<N) rowptr[i] = sd[t]-v;           // exclusive within chunk
    if (t==TPB-1) bsum[blockIdx.x] = sd[t];
}

__global__ __launch_bounds__(TPB) void k_scanB(const int* __restrict__ bsum, int* __restrict__ boff, int nb){
    __shared__ int sd[TPB];
    const int t = threadIdx.x;
    int v = (t<nb)? bsum[t] : 0;
    sd[t]=v; __syncthreads();
    for (int off=1; off<TPB; off<<=1){
        int x = (t>=off)? sd[t-off] : 0; __syncthreads();
        sd[t] += x; __syncthreads();
    }
    if (t<nb) boff[t] = sd[t]-v;
}

__global__ __launch_bounds__(TPB) void k_scanC(int* __restrict__ rowptr, int* __restrict__ cursor,
                                               const int* __restrict__ boff, int N, int E){
    const int i = blockIdx.x*TPB + threadIdx.x;
    if (i<N){ int v = rowptr[i] + boff[blockIdx.x]; rowptr[i]=v; cursor[i]=v; }
    if (i==0) rowptr[N]=E;
}

__global__ __launch_bounds__(TPB) void k_pos(const int* __restrict__ ei, int* __restrict__ cursor,
                                             int* __restrict__ csr_eid, int* __restrict__ csr_col, int E){
    for (int e = blockIdx.x*TPB + threadIdx.x; e < E; e += gridDim.x*TPB){
        int r = ei[e];
        int p = atomicAdd(&cursor[r], 1);
        csr_eid[p] = e;
        csr_col[p] = ei[E+e];
    }
}

// ---------------- K edge elementwise: eij[i](=Ce+bC) += Dx[row] + Ex[col] ----------------
__global__ __launch_bounds__(TPB) void k_edge2(
    const int* __restrict__ ei, const float* __restrict__ Dx, const float* __restrict__ Ex,
    float* __restrict__ eij, int E)
{
    const long i = (long)blockIdx.x*TPB + threadIdx.x;
    if (i >= (long)E*16) return;
    const int e = (int)(i>>4); const int jc = (int)(i&15);
    const int r = ei[e], c = ei[E+e];
    float4 v = ((float4*)eij)[i];
    float4 d = ((const float4*)Dx)[(size_t)r*16+jc];
    float4 f = ((const float4*)Ex)[(size_t)c*16+jc];
    v.x+=d.x+f.x; v.y+=d.y+f.y; v.z+=d.z+f.z; v.w+=d.w+f.w;
    ((float4*)eij)[i] = v;
}

// ---------------- aggregation: xt[n] = Ax[n] + sum_csr sigm(eij[eid])*Bx[col] ----------------
// one wave per node; 4 lane-groups x 16 lanes (float4 each); shfl reduce across groups.
__global__ __launch_bounds__(TPB) void k_aggr(
    const float* __restrict__ AxB, const float* __restrict__ Bx,
    const float* __restrict__ eij, const int* __restrict__ csr_eid,
    const int* __restrict__ csr_col, const int* __restrict__ rowptr,
    float* __restrict__ xt, int N)
{
    const int tid = threadIdx.x;
    const int n = blockIdx.x*4 + (tid>>6);
    if (n >= N) return;
    const int lane = tid&63, g = lane>>4, l = lane&15;
    const int rp0 = rowptr[n], rp1 = rowptr[n+1];
    float acc[4] = {0.f,0.f,0.f,0.f};
    const float4* e4=(const float4*)eij;
    const float4* b4=(const float4*)Bx;
    for (int k = rp0+g; k < rp1; k += 4){
        const int eid = csr_eid[k], col = csr_col[k];
        float v[4]; *(float4*)v = e4[(size_t)eid*16 + l];
        float b[4]; *(float4*)b = b4[(size_t)col*16 + l];
        #pragma unroll
        for (int c=0;c<4;c++) acc[c] += b[c]*sigm(v[c]);
    }
    #pragma unroll
    for (int off=16; off<64; off<<=1){
        #pragma unroll
        for (int c=0;c<4;c++) acc[c] += __shfl_xor(acc[c], off, 64);
    }
    if (g==0){
        float a[4]; *(float4*)a = ((const float4*)AxB)[(size_t)n*16+l];
        float o[4];
        #pragma unroll
        for (int c=0;c<4;c++) o[c] = a[c]+acc[c];
        ((float4*)xt)[(size_t)n*16+l] = *(float4*)o;
    }
}

// ---------------- column stats partials: part[bid][0:64]=sum, [64:128]=sumsq ----------------
__global__ __launch_bounds__(TPB) void k_part(
    const float* __restrict__ src, float* __restrict__ part, long nrows)
{
    const int tid = threadIdx.x;
    const int jg = tid & 15;
    const int wv = tid >> 6;
    const int g  = (tid >> 4) & 3;
    float s[4]={0,0,0,0}, q[4]={0,0,0,0};
    const float4* s4 = (const float4*)src;
    const long rstep = (long)gridDim.x*16;
    for (long r = (long)blockIdx.x*16 + (wv*4+g); r < nrows; r += rstep){
        float v[4]; *(float4*)v = s4[r*16 + jg];
        #pragma unroll
        for (int c=0;c<4;c++){ s[c]+=v[c]; q[c]+=v[c]*v[c]; }
    }
    #pragma unroll
    for (int off=16; off<64; off<<=1){
        #pragma unroll
        for (int c=0;c<4;c++){ s[c]+=__shfl_xor(s[c],off,64); q[c]+=__shfl_xor(q[c],off,64); }
    }
    __shared__ float ls[4][128];
    if (g==0){
        #pragma unroll
        for (int c=0;c<4;c++){ ls[wv][jg*4+c]=s[c]; ls[wv][64+jg*4+c]=q[c]; }
    }
    __syncthreads();
    if (tid<128)
        part[(long)blockIdx.x*128 + tid] = ls[0][tid]+ls[1][tid]+ls[2][tid]+ls[3][tid];
}

__global__ void k_red(const float* __restrict__ part, float* __restrict__ st, int G){
    const int tid = threadIdx.x; // 128
    float s = 0.f;
    for (int b=0;b<G;b++) s += part[(long)b*128 + tid];
    st[tid] = s;
}

// ---------------- xf = x + relu(bn(xt)) ----------------
__global__ __launch_bounds__(TPB) void k_xupdate(
    const float* __restrict__ x, const float* __restrict__ xt,
    const float* __restrict__ stin, const float* __restrict__ gx, const float* __restrict__ bx,
    float* __restrict__ xf, int N)
{
    __shared__ float m_[64], r_[64], gl[64], bl[64];
    const int tid=threadIdx.x;
    if (tid<64){
        float mm=stin[tid]/(float)N;
        float vv=stin[64+tid]/(float)N - mm*mm;
        m_[tid]=mm; r_[tid]=rsqrtf(vv+EPSV);
        gl[tid]=gx[tid]; bl[tid]=bx[tid];
    }
    __syncthreads();
    const int i4 = blockIdx.x*TPB+tid;
    if (i4 >= N*16) return;
    const int jg = i4&15;
    float a[4]; *(float4*)a = ((const float4*)x)[i4];
    float t[4]; *(float4*)t = ((const float4*)xt)[i4];
    float o[4];
    #pragma unroll
    for (int c=0;c<4;c++){
        int j=jg*4+c;
        float xn = gl[j]*((t[c]-m_[j])*r_[j]) + bl[j];
        o[c]=a[c]+fmaxf(xn,0.f);
    }
    ((float4*)xf)[i4] = *(float4*)o;
}

// ---------------- FFN1: h1 = relu(bn1(xf) @ W1.T + b1) ----------------
__global__ __launch_bounds__(TPB) void k_ffn1(
    const float* __restrict__ xf, const float* __restrict__ stxf,
    const float* __restrict__ g1, const float* __restrict__ b1n,
    const float* __restrict__ W1, const float* __restrict__ b1,
    float* __restrict__ h1, int N)
{
    __shared__ float Wl[4096];
    __shared__ float m_[64], r_[64], gl[64], bl[64], bj[64];
    const int tid=threadIdx.x;
    const int half=blockIdx.y;
    {
        const float4* Wg=(const float4*)(W1 + (size_t)half*4096);
        float4* Wd=(float4*)Wl;
        #pragma unroll
        for (int i=0;i<4;i++) Wd[tid+i*TPB]=Wg[tid+i*TPB];
        if (tid<64){
            float mm=stxf[tid]/(float)N;
            float vv=stxf[64+tid]/(float)N - mm*mm;
            m_[tid]=mm; r_[tid]=rsqrtf(vv+EPSV);
            gl[tid]=g1[tid]; bl[tid]=b1n[tid];
            bj[tid]=b1[half*64+tid];
        }
    }
    __syncthreads();
    const int r = blockIdx.x*TPB+tid;
    if (r>=N) return;
    float xn[64];
    {
        const float4* x4=(const float4*)xf + (size_t)r*16;
        #pragma unroll
        for (int i=0;i<16;i++){
            float t[4]; *(float4*)t = x4[i];
            #pragma unroll
            for (int c=0;c<4;c++){
                int k=i*4+c;
                xn[k] = gl[k]*((t[c]-m_[k])*r_[k]) + bl[k];
            }
        }
    }
    float4* o4=(float4*)h1 + (size_t)r*32 + half*16;
    const float4* Wl4=(const float4*)Wl;
    for (int jc=0;jc<8;jc++){
        float acc[8];
        #pragma unroll
        for (int jj=0;jj<8;jj++) acc[jj]=bj[jc*8+jj];
        #pragma unroll
        for (int kc=0;kc<16;kc++){
            #pragma unroll
            for (int jj=0;jj<8;jj++){
                float4 w=Wl4[(jc*8+jj)*16+kc];
                acc[jj]=fmaf(xn[kc*4],w.x,fmaf(xn[kc*4+1],w.y,fmaf(xn[kc*4+2],w.z,fmaf(xn[kc*4+3],w.w,acc[jj]))));
            }
        }
        #pragma unroll
        for (int jj=0;jj<8;jj++) acc[jj]=fmaxf(acc[jj],0.f);
        float4 q0={acc[0],acc[1],acc[2],acc[3]};
        float4 q1={acc[4],acc[5],acc[6],acc[7]};
        o4[jc*2]=q0; o4[jc*2+1]=q1;
    }
}

// ---------------- FFN2: y = xf + (h1 @ W2.T + b2) ----------------
__global__ __launch_bounds__(TPB) void k_ffn2(
    const float* __restrict__ h1, const float* __restrict__ xf,
    const float* __restrict__ W2, const float* __restrict__ b2,
    float* __restrict__ y, int N)
{
    __shared__ float Wl[4096];
    __shared__ float bj[32];
    const int tid=threadIdx.x;
    const int half=blockIdx.y;
    {
        const float4* Wg=(const float4*)(W2 + (size_t)half*32*128);
        float4* Wd=(float4*)Wl;
        #pragma unroll
        for (int i=0;i<4;i++) Wd[tid+i*TPB]=Wg[tid+i*TPB];
        if (tid<32) bj[tid]=b2[half*32+tid];
    }
    __syncthreads();
    const int r=blockIdx.x*TPB+tid;
    if (r>=N) return;
    float acc[32];
    #pragma unroll
    for (int j=0;j<32;j++) acc[j]=bj[j];
    const float4* hr=(const float4*)h1 + (size_t)r*32;
    const float4* Wl4=(const float4*)Wl;
    #pragma unroll 4
    for (int kc=0;kc<32;kc++){
        float t[4]; *(float4*)t = hr[kc];
        #pragma unroll
        for (int j=0;j<32;j++){
            float4 w=Wl4[j*32+kc];
            acc[j]=fmaf(t[0],w.x,fmaf(t[1],w.y,fmaf(t[2],w.z,fmaf(t[3],w.w,acc[j]))));
        }
    }
    const float4* xr4=(const float4*)xf + (size_t)r*16 + half*8;
    float4* y4=(float4*)y + (size_t)r*16 + half*8;
    #pragma unroll
    for (int jc=0;jc<8;jc++){
        float t[4]; *(float4*)t = xr4[jc];
        float o[4];
        o[0]=t[0]+acc[jc*4];   o[1]=t[1]+acc[jc*4+1];
        o[2]=t[2]+acc[jc*4+2]; o[3]=t[3]+acc[jc*4+3];
        y4[jc] = *(float4*)o;
    }
}

// ---------------- out_x = bn2(y) ----------------
__global__ __launch_bounds__(TPB) void k_bnout(
    const float* __restrict__ y, const float* __restrict__ sty,
    const float* __restrict__ g2, const float* __restrict__ b2n,
    float* __restrict__ outx, int N)
{
    __shared__ float m_[64], r_[64], gl[64], bl[64];
    const int tid=threadIdx.x;
    if (tid<64){
        float mm=sty[tid]/(float)N;
        float vv=sty[64+tid]/(float)N - mm*mm;
        m_[tid]=mm; r_[tid]=rsqrtf(vv+EPSV);
        gl[tid]=g2[tid]; bl[tid]=b2n[tid];
    }
    __syncthreads();
    const int i4=blockIdx.x*TPB+tid;
    if (i4 >= N*16) return;
    const int jg=i4&15;
    float t[4]; *(float4*)t = ((const float4*)y)[i4];
    float o[4];
    #pragma unroll
    for (int c=0;c<4;c++){
        int j=jg*4+c;
        o[c] = gl[j]*((t[c]-m_[j])*r_[j]) + bl[j];
    }
    ((float4*)outx)[i4] = *(float4*)o;
}

// ---------------- e_final = edge_attr + relu(bn_e(e_ij)) in-place ----------------
__global__ __launch_bounds__(TPB) void k_efinal(
    const float* __restrict__ ea, float* __restrict__ eio,
    const float* __restrict__ ste, const float* __restrict__ ge, const float* __restrict__ be,
    int E)
{
    __shared__ float m_[64], r_[64], gl[64], bl[64];
    const int tid=threadIdx.x;
    if (tid<64){
        float mm=ste[tid]/(float)E;
        float vv=ste[64+tid]/(float)E - mm*mm;
        m_[tid]=mm; r_[tid]=rsqrtf(vv+EPSV);
        gl[tid]=ge[tid]; bl[tid]=be[tid];
    }
    __syncthreads();
    const long i4=(long)blockIdx.x*TPB+tid;
    if (i4 >= (long)E*16) return;
    const int jg=(int)(i4&15);
    float t[4]; *(float4*)t = ((float4*)eio)[i4];
    float a[4]; *(float4*)a = ((const float4*)ea)[i4];
    float o[4];
    #pragma unroll
    for (int c=0;c<4;c++){
        int j=jg*4+c;
        float xn = gl[j]*((t[c]-m_[j])*r_[j]) + bl[j];
        o[c]=a[c]+fmaxf(xn,0.f);
    }
    ((float4*)eio)[i4] = *(float4*)o;
}

extern "C" void kernel_launch(void* const* d_in, const int* in_sizes, int n_in,
                              void* d_out, int out_size, void* d_ws, size_t ws_size,
                              hipStream_t stream)
{
    const float* x   = (const float*)d_in[0];
    const int*   ei  = (const int*)  d_in[1];
    const float* ea  = (const float*)d_in[2];
    const float* WA  = (const float*)d_in[3];  const float* bA  = (const float*)d_in[4];
    const float* WB  = (const float*)d_in[5];  const float* bB  = (const float*)d_in[6];
    const float* WC  = (const float*)d_in[7];  const float* bC  = (const float*)d_in[8];
    const float* WD  = (const float*)d_in[9];  const float* bD  = (const float*)d_in[10];
    const float* WE  = (const float*)d_in[11]; const float* bE  = (const float*)d_in[12];
    const float* g_x = (const float*)d_in[13]; const float* b_x = (const float*)d_in[14];
    const float* g_e = (const float*)d_in[15]; const float* b_e = (const float*)d_in[16];
    const float* g_n1= (const float*)d_in[17]; const float* b_n1= (const float*)d_in[18];
    const float* W1  = (const float*)d_in[19]; const float* b1  = (const float*)d_in[20];
    const float* W2  = (const float*)d_in[21]; const float* b2  = (const float*)d_in[22];
    const float* g_n2= (const float*)d_in[23]; const float* b_n2= (const float*)d_in[24];

    const int N = in_sizes[0]/64;
    const int E = in_sizes[2]/64;

    // ---- workspace layout (~72 MB) ----
    float* ws   = (float*)d_ws;
    float* AxB  = ws;                        // [N,64]; reused as xf after k_aggr
    float* Bx   = AxB + (size_t)N*64;        // [N,64]; reused as yv after k_aggr
    float* Dx   = Bx  + (size_t)N*64;        // [N,64] ┐ reused as h1 [N,128] after k_edge2
    float* Ex   = Dx  + (size_t)N*64;        // [N,64] ┘
    float* xt   = Ex  + (size_t)N*64;        // [N,64]
    float* st   = xt  + (size_t)N*64;        // 512 floats: [e|xt|xf|y] x (sum64,sumsq64)
    float* part = st + 512;                  // 2048*128 floats
    int*   deg    = (int*)(part + 2048*128); // N
    int*   rowptr = deg + N;                 // N+1
    int*   cursor = rowptr + (N+1);          // N
    int*   bsumB  = cursor + N;              // 256
    int*   boffB  = bsumB + 256;             // 256
    int*   csr_eid= boffB + 256;             // E
    int*   csr_col= csr_eid + E;             // E

    float* xf = AxB;
    float* yv = Bx;
    float* h1 = Dx;

    float* st_e  = st;
    float* st_xt = st + 128;
    float* st_xf = st + 256;
    float* st_y  = st + 384;

    float* outx = (float*)d_out;             // [N,64]
    float* eij  = outx + (size_t)N*64;       // [E,64]: Ce -> e_ij -> e_final in-place

    const int nbN    = (N+TPB-1)/TPB;
    const int nbE    = (E+TPB-1)/TPB;
    const int nbN16  = (N*16+TPB-1)/TPB;
    const long e16   = (long)E*16;
    const int nbE16  = (int)((e16+TPB-1)/TPB);
    const int nchunk = (N+TPB-1)/TPB;        // 196 for N=50000 (must be <= 256)

    hipMemsetAsync(deg, 0, (size_t)N*sizeof(int), stream);

    // node GEMMs + Ce (Ce lands directly in the e_ij output region)
    k_rowgemm<<<nbN, TPB, 0, stream>>>(x,  WA, bA, AxB, N);
    k_rowgemm<<<nbN, TPB, 0, stream>>>(x,  WB, bB, Bx,  N);
    k_rowgemm<<<nbN, TPB, 0, stream>>>(x,  WD, bD, Dx,  N);
    k_rowgemm<<<nbN, TPB, 0, stream>>>(x,  WE, bE, Ex,  N);
    k_rowgemm<<<nbE, TPB, 0, stream>>>(ea, WC, bC, eij, E);

    // CSR build
    k_hist <<<2048, TPB, 0, stream>>>(ei, deg, E);
    k_scanA<<<nchunk, TPB, 0, stream>>>(deg, rowptr, bsumB, N);
    k_scanB<<<1, TPB, 0, stream>>>(bsumB, boffB, nchunk);
    k_scanC<<<nchunk, TPB, 0, stream>>>(rowptr, cursor, boffB, N, E);
    k_pos  <<<2048, TPB, 0, stream>>>(ei, cursor, csr_eid, csr_col, E);

    // e_ij = Ce + Dx[row] + Ex[col]   (elementwise, coalesced)
    k_edge2<<<nbE16, TPB, 0, stream>>>(ei, Dx, Ex, eij, E);

    // e_ij stats
    k_part<<<2048, TPB, 0, stream>>>(eij, part, (long)E);
    k_red <<<1, 128, 0, stream>>>(part, st_e, 2048);

    // atomic-free aggregation: xt = Ax + sum sigm(eij)*Bx[col]
    k_aggr<<<(N+3)/4, TPB, 0, stream>>>(AxB, Bx, eij, csr_eid, csr_col, rowptr, xt, N);

    k_part<<<512, TPB, 0, stream>>>(xt, part, (long)N);
    k_red <<<1, 128, 0, stream>>>(part, st_xt, 512);

    k_xupdate<<<nbN16, TPB, 0, stream>>>(x, xt, st_xt, g_x, b_x, xf, N);

    k_part<<<512, TPB, 0, stream>>>(xf, part, (long)N);
    k_red <<<1, 128, 0, stream>>>(part, st_xf, 512);

    k_ffn1<<<dim3(nbN,2), TPB, 0, stream>>>(xf, st_xf, g_n1, b_n1, W1, b1, h1, N);
    k_ffn2<<<dim3(nbN,2), TPB, 0, stream>>>(h1, xf, W2, b2, yv, N);

    k_part<<<512, TPB, 0, stream>>>(yv, part, (long)N);
    k_red <<<1, 128, 0, stream>>>(part, st_y, 512);

    k_bnout <<<nbN16, TPB, 0, stream>>>(yv, st_y, g_n2, b_n2, outx, N);
    k_efinal<<<nbE16, TPB, 0, stream>>>(ea, eij, st_e, g_e, b_e, E);
}

// Round 3
// 1090.591 us; speedup vs baseline: 7.3480x; 1.7451x over previous
//
#include <hip/hip_runtime.h>

#define TPB 256
#define EPSV 1e-5f
#define RCH 16

__device__ __forceinline__ float sigm(float x){ return 1.0f/(1.0f + __expf(-x)); }

// ---------------- generic row GEMM: out[r] = src[r] @ W.T + b (64x64) ----------------
__global__ __launch_bounds__(TPB) void k_rowgemm(
    const float* __restrict__ src, const float* __restrict__ W, const float* __restrict__ b,
    float* __restrict__ out, int rows)
{
    __shared__ float Wl[4096];
    __shared__ float bl[64];
    const int tid = threadIdx.x;
    {
        const float4* Wg=(const float4*)W; float4* Wd=(float4*)Wl;
        #pragma unroll
        for (int i=0;i<4;i++) Wd[tid + i*TPB] = Wg[tid + i*TPB];
        if (tid<64) bl[tid]=b[tid];
    }
    __syncthreads();
    const int r = blockIdx.x*TPB + tid;
    if (r >= rows) return;
    float xr[64];
    {
        const float4* x4=(const float4*)src + (size_t)r*16;
        #pragma unroll
        for (int i=0;i<16;i++){ float4 t=x4[i]; xr[i*4]=t.x; xr[i*4+1]=t.y; xr[i*4+2]=t.z; xr[i*4+3]=t.w; }
    }
    float4* o4=(float4*)out + (size_t)r*16;
    const float4* Wl4=(const float4*)Wl;
    for (int jc=0;jc<8;jc++){
        float acc[8];
        #pragma unroll
        for (int jj=0;jj<8;jj++) acc[jj]=bl[jc*8+jj];
        #pragma unroll
        for (int kc=0;kc<16;kc++){
            #pragma unroll
            for (int jj=0;jj<8;jj++){
                float4 w=Wl4[(jc*8+jj)*16+kc];
                acc[jj]=fmaf(xr[kc*4],w.x,fmaf(xr[kc*4+1],w.y,fmaf(xr[kc*4+2],w.z,fmaf(xr[kc*4+3],w.w,acc[jj]))));
            }
        }
        float4 q0={acc[0],acc[1],acc[2],acc[3]};
        float4 q1={acc[4],acc[5],acc[6],acc[7]};
        o4[jc*2]=q0; o4[jc*2+1]=q1;
    }
}

// ---------------- CSR build ----------------
__global__ __launch_bounds__(TPB) void k_hist(const int* __restrict__ ei, int* __restrict__ deg, int E){
    for (int e = blockIdx.x*TPB + threadIdx.x; e < E; e += gridDim.x*TPB)
        atomicAdd(&deg[ei[e]], 1);
}

__global__ __launch_bounds__(TPB) void k_scanA(const int* __restrict__ deg, int* __restrict__ rowptr,
                                               int* __restrict__ bsum, int N){
    __shared__ int sd[TPB];
    const int t = threadIdx.x; const int i = blockIdx.x*TPB + t;
    int v = (i<N)? deg[i] : 0;
    sd[t]=v; __syncthreads();
    for (int off=1; off<TPB; off<<=1){
        int x = (t>=off)? sd[t-off] : 0; __syncthreads();
        sd[t] += x; __syncthreads();
    }
    if (i<N) rowptr[i] = sd[t]-v;
    if (t==TPB-1) bsum[blockIdx.x] = sd[t];
}

__global__ __launch_bounds__(TPB) void k_scanB(const int* __restrict__ bsum, int* __restrict__ boff, int nb){
    __shared__ int sd[TPB];
    const int t = threadIdx.x;
    int v = (t<nb)? bsum[t] : 0;
    sd[t]=v; __syncthreads();
    for (int off=1; off<TPB; off<<=1){
        int x = (t>=off)? sd[t-off] : 0; __syncthreads();
        sd[t] += x; __syncthreads();
    }
    if (t<nb) boff[t] = sd[t]-v;
}

__global__ __launch_bounds__(TPB) void k_scanC(int* __restrict__ rowptr, int* __restrict__ cursor,
                                               const int* __restrict__ boff, int N, int E){
    const int i = blockIdx.x*TPB + threadIdx.x;
    if (i<N){ int v = rowptr[i] + boff[blockIdx.x]; rowptr[i]=v; cursor[i]=v; }
    if (i==0) rowptr[N]=E;
}

__global__ __launch_bounds__(TPB) void k_pos(const int* __restrict__ ei, int* __restrict__ cursor,
                                             int* __restrict__ csr_eid, int* __restrict__ csr_col, int E){
    for (int e = blockIdx.x*TPB + threadIdx.x; e < E; e += gridDim.x*TPB){
        int r = ei[e];
        int p = atomicAdd(&cursor[r], 1);
        csr_eid[p] = e;
        csr_col[p] = ei[E+e];
    }
}

// ---------------- eij[i](=Ce+bC) += Dx[row] + Ex[col] ----------------
__global__ __launch_bounds__(TPB) void k_edge2(
    const int* __restrict__ ei, const float* __restrict__ Dx, const float* __restrict__ Ex,
    float* __restrict__ eij, int E)
{
    const long i = (long)blockIdx.x*TPB + threadIdx.x;
    if (i >= (long)E*16) return;
    const int e = (int)(i>>4); const int jc = (int)(i&15);
    const int r = ei[e], c = ei[E+e];
    float4 v = ((float4*)eij)[i];
    float4 d = ((const float4*)Dx)[(size_t)r*16+jc];
    float4 f = ((const float4*)Ex)[(size_t)c*16+jc];
    v.x+=d.x+f.x; v.y+=d.y+f.y; v.z+=d.z+f.z; v.w+=d.w+f.w;
    ((float4*)eij)[i] = v;
}

// ---------------- aggregation: xt[n] = Ax[n] + sum_csr sigm(eij[eid])*Bx[col] ----------------
__global__ __launch_bounds__(TPB) void k_aggr(
    const float* __restrict__ AxB, const float* __restrict__ Bx,
    const float* __restrict__ eij, const int* __restrict__ csr_eid,
    const int* __restrict__ csr_col, const int* __restrict__ rowptr,
    float* __restrict__ xt, int N)
{
    const int tid = threadIdx.x;
    const int n = blockIdx.x*4 + (tid>>6);
    if (n >= N) return;
    const int lane = tid&63, g = lane>>4, l = lane&15;
    const int rp0 = rowptr[n], rp1 = rowptr[n+1];
    float acc[4] = {0.f,0.f,0.f,0.f};
    const float4* e4=(const float4*)eij;
    const float4* b4=(const float4*)Bx;
    for (int k = rp0+g; k < rp1; k += 4){
        const int eid = csr_eid[k], col = csr_col[k];
        float v[4]; *(float4*)v = e4[(size_t)eid*16 + l];
        float b[4]; *(float4*)b = b4[(size_t)col*16 + l];
        #pragma unroll
        for (int c=0;c<4;c++) acc[c] += b[c]*sigm(v[c]);
    }
    #pragma unroll
    for (int off=16; off<64; off<<=1){
        #pragma unroll
        for (int c=0;c<4;c++) acc[c] += __shfl_xor(acc[c], off, 64);
    }
    if (g==0){
        float a[4]; *(float4*)a = ((const float4*)AxB)[(size_t)n*16+l];
        float o[4];
        #pragma unroll
        for (int c=0;c<4;c++) o[c] = a[c]+acc[c];
        ((float4*)xt)[(size_t)n*16+l] = *(float4*)o;
    }
}

// ---------------- column stats partials: part[bid][0:64]=sum, [64:128]=sumsq ----------------
__global__ __launch_bounds__(TPB) void k_part(
    const float* __restrict__ src, float* __restrict__ part, long nrows)
{
    const int tid = threadIdx.x;
    const int jg = tid & 15;
    const int wv = tid >> 6;
    const int g  = (tid >> 4) & 3;
    float s[4]={0,0,0,0}, q[4]={0,0,0,0};
    const float4* s4 = (const float4*)src;
    const long rstep = (long)gridDim.x*16;
    for (long r = (long)blockIdx.x*16 + (wv*4+g); r < nrows; r += rstep){
        float v[4]; *(float4*)v = s4[r*16 + jg];
        #pragma unroll
        for (int c=0;c<4;c++){ s[c]+=v[c]; q[c]+=v[c]*v[c]; }
    }
    #pragma unroll
    for (int off=16; off<64; off<<=1){
        #pragma unroll
        for (int c=0;c<4;c++){ s[c]+=__shfl_xor(s[c],off,64); q[c]+=__shfl_xor(q[c],off,64); }
    }
    __shared__ float ls[4][128];
    if (g==0){
        #pragma unroll
        for (int c=0;c<4;c++){ ls[wv][jg*4+c]=s[c]; ls[wv][64+jg*4+c]=q[c]; }
    }
    __syncthreads();
    if (tid<128)
        part[(long)blockIdx.x*128 + tid] = ls[0][tid]+ls[1][tid]+ls[2][tid]+ls[3][tid];
}

// ---------------- parallel partial reduce: grid = G/RCH blocks, coalesced, atomic tail ----------------
__global__ __launch_bounds__(TPB) void k_red2(
    const float* __restrict__ part, float* __restrict__ st, int G)
{
    const int t = threadIdx.x;
    const int j  = t & 127;      // counter column
    const int rg = t >> 7;       // 0..1 row-group
    const long base = (long)blockIdx.x * RCH;
    float s = 0.f;
    #pragma unroll
    for (int r = rg; r < RCH; r += 2)
        s += part[(base + r)*128 + j];
    __shared__ float sd[TPB];
    sd[t] = s; __syncthreads();
    if (t < 128)
        unsafeAtomicAdd(&st[t], sd[t] + sd[t+128]);
}

// ---------------- xf = x + relu(bn(xt)) ----------------
__global__ __launch_bounds__(TPB) void k_xupdate(
    const float* __restrict__ x, const float* __restrict__ xt,
    const float* __restrict__ stin, const float* __restrict__ gx, const float* __restrict__ bx,
    float* __restrict__ xf, int N)
{
    __shared__ float m_[64], r_[64], gl[64], bl[64];
    const int tid=threadIdx.x;
    if (tid<64){
        float mm=stin[tid]/(float)N;
        float vv=stin[64+tid]/(float)N - mm*mm;
        m_[tid]=mm; r_[tid]=rsqrtf(vv+EPSV);
        gl[tid]=gx[tid]; bl[tid]=bx[tid];
    }
    __syncthreads();
    const int i4 = blockIdx.x*TPB+tid;
    if (i4 >= N*16) return;
    const int jg = i4&15;
    float a[4]; *(float4*)a = ((const float4*)x)[i4];
    float t[4]; *(float4*)t = ((const float4*)xt)[i4];
    float o[4];
    #pragma unroll
    for (int c=0;c<4;c++){
        int j=jg*4+c;
        float xn = gl[j]*((t[c]-m_[j])*r_[j]) + bl[j];
        o[c]=a[c]+fmaxf(xn,0.f);
    }
    ((float4*)xf)[i4] = *(float4*)o;
}

// ---------------- FFN1: h1 = relu(bn1(xf) @ W1.T + b1) ----------------
__global__ __launch_bounds__(TPB) void k_ffn1(
    const float* __restrict__ xf, const float* __restrict__ stxf,
    const float* __restrict__ g1, const float* __restrict__ b1n,
    const float* __restrict__ W1, const float* __restrict__ b1,
    float* __restrict__ h1, int N)
{
    __shared__ float Wl[4096];
    __shared__ float m_[64], r_[64], gl[64], bl[64], bj[64];
    const int tid=threadIdx.x;
    const int half=blockIdx.y;
    {
        const float4* Wg=(const float4*)(W1 + (size_t)half*4096);
        float4* Wd=(float4*)Wl;
        #pragma unroll
        for (int i=0;i<4;i++) Wd[tid+i*TPB]=Wg[tid+i*TPB];
        if (tid<64){
            float mm=stxf[tid]/(float)N;
            float vv=stxf[64+tid]/(float)N - mm*mm;
            m_[tid]=mm; r_[tid]=rsqrtf(vv+EPSV);
            gl[tid]=g1[tid]; bl[tid]=b1n[tid];
            bj[tid]=b1[half*64+tid];
        }
    }
    __syncthreads();
    const int r = blockIdx.x*TPB+tid;
    if (r>=N) return;
    float xn[64];
    {
        const float4* x4=(const float4*)xf + (size_t)r*16;
        #pragma unroll
        for (int i=0;i<16;i++){
            float t[4]; *(float4*)t = x4[i];
            #pragma unroll
            for (int c=0;c<4;c++){
                int k=i*4+c;
                xn[k] = gl[k]*((t[c]-m_[k])*r_[k]) + bl[k];
            }
        }
    }
    float4* o4=(float4*)h1 + (size_t)r*32 + half*16;
    const float4* Wl4=(const float4*)Wl;
    for (int jc=0;jc<8;jc++){
        float acc[8];
        #pragma unroll
        for (int jj=0;jj<8;jj++) acc[jj]=bj[jc*8+jj];
        #pragma unroll
        for (int kc=0;kc<16;kc++){
            #pragma unroll
            for (int jj=0;jj<8;jj++){
                float4 w=Wl4[(jc*8+jj)*16+kc];
                acc[jj]=fmaf(xn[kc*4],w.x,fmaf(xn[kc*4+1],w.y,fmaf(xn[kc*4+2],w.z,fmaf(xn[kc*4+3],w.w,acc[jj]))));
            }
        }
        #pragma unroll
        for (int jj=0;jj<8;jj++) acc[jj]=fmaxf(acc[jj],0.f);
        float4 q0={acc[0],acc[1],acc[2],acc[3]};
        float4 q1={acc[4],acc[5],acc[6],acc[7]};
        o4[jc*2]=q0; o4[jc*2+1]=q1;
    }
}

// ---------------- FFN2: y = xf + (h1 @ W2.T + b2) ----------------
__global__ __launch_bounds__(TPB) void k_ffn2(
    const float* __restrict__ h1, const float* __restrict__ xf,
    const float* __restrict__ W2, const float* __restrict__ b2,
    float* __restrict__ y, int N)
{
    __shared__ float Wl[4096];
    __shared__ float bj[32];
    const int tid=threadIdx.x;
    const int half=blockIdx.y;
    {
        const float4* Wg=(const float4*)(W2 + (size_t)half*32*128);
        float4* Wd=(float4*)Wl;
        #pragma unroll
        for (int i=0;i<4;i++) Wd[tid+i*TPB]=Wg[tid+i*TPB];
        if (tid<32) bj[tid]=b2[half*32+tid];
    }
    __syncthreads();
    const int r=blockIdx.x*TPB+tid;
    if (r>=N) return;
    float acc[32];
    #pragma unroll
    for (int j=0;j<32;j++) acc[j]=bj[j];
    const float4* hr=(const float4*)h1 + (size_t)r*32;
    const float4* Wl4=(const float4*)Wl;
    #pragma unroll 4
    for (int kc=0;kc<32;kc++){
        float t[4]; *(float4*)t = hr[kc];
        #pragma unroll
        for (int j=0;j<32;j++){
            float4 w=Wl4[j*32+kc];
            acc[j]=fmaf(t[0],w.x,fmaf(t[1],w.y,fmaf(t[2],w.z,fmaf(t[3],w.w,acc[j]))));
        }
    }
    const float4* xr4=(const float4*)xf + (size_t)r*16 + half*8;
    float4* y4=(float4*)y + (size_t)r*16 + half*8;
    #pragma unroll
    for (int jc=0;jc<8;jc++){
        float t[4]; *(float4*)t = xr4[jc];
        float o[4];
        o[0]=t[0]+acc[jc*4];   o[1]=t[1]+acc[jc*4+1];
        o[2]=t[2]+acc[jc*4+2]; o[3]=t[3]+acc[jc*4+3];
        y4[jc] = *(float4*)o;
    }
}

// ---------------- out_x = bn2(y) ----------------
__global__ __launch_bounds__(TPB) void k_bnout(
    const float* __restrict__ y, const float* __restrict__ sty,
    const float* __restrict__ g2, const float* __restrict__ b2n,
    float* __restrict__ outx, int N)
{
    __shared__ float m_[64], r_[64], gl[64], bl[64];
    const int tid=threadIdx.x;
    if (tid<64){
        float mm=sty[tid]/(float)N;
        float vv=sty[64+tid]/(float)N - mm*mm;
        m_[tid]=mm; r_[tid]=rsqrtf(vv+EPSV);
        gl[tid]=g2[tid]; bl[tid]=b2n[tid];
    }
    __syncthreads();
    const int i4=blockIdx.x*TPB+tid;
    if (i4 >= N*16) return;
    const int jg=i4&15;
    float t[4]; *(float4*)t = ((const float4*)y)[i4];
    float o[4];
    #pragma unroll
    for (int c=0;c<4;c++){
        int j=jg*4+c;
        o[c] = gl[j]*((t[c]-m_[j])*r_[j]) + bl[j];
    }
    ((float4*)outx)[i4] = *(float4*)o;
}

// ---------------- e_final = edge_attr + relu(bn_e(e_ij)) in-place ----------------
__global__ __launch_bounds__(TPB) void k_efinal(
    const float* __restrict__ ea, float* __restrict__ eio,
    const float* __restrict__ ste, const float* __restrict__ ge, const float* __restrict__ be,
    int E)
{
    __shared__ float m_[64], r_[64], gl[64], bl[64];
    const int tid=threadIdx.x;
    if (tid<64){
        float mm=ste[tid]/(float)E;
        float vv=ste[64+tid]/(float)E - mm*mm;
        m_[tid]=mm; r_[tid]=rsqrtf(vv+EPSV);
        gl[tid]=ge[tid]; bl[tid]=be[tid];
    }
    __syncthreads();
    const long i4=(long)blockIdx.x*TPB+tid;
    if (i4 >= (long)E*16) return;
    const int jg=(int)(i4&15);
    float t[4]; *(float4*)t = ((float4*)eio)[i4];
    float a[4]; *(float4*)a = ((const float4*)ea)[i4];
    float o[4];
    #pragma unroll
    for (int c=0;c<4;c++){
        int j=jg*4+c;
        float xn = gl[j]*((t[c]-m_[j])*r_[j]) + bl[j];
        o[c]=a[c]+fmaxf(xn,0.f);
    }
    ((float4*)eio)[i4] = *(float4*)o;
}

extern "C" void kernel_launch(void* const* d_in, const int* in_sizes, int n_in,
                              void* d_out, int out_size, void* d_ws, size_t ws_size,
                              hipStream_t stream)
{
    const float* x   = (const float*)d_in[0];
    const int*   ei  = (const int*)  d_in[1];
    const float* ea  = (const float*)d_in[2];
    const float* WA  = (const float*)d_in[3];  const float* bA  = (const float*)d_in[4];
    const float* WB  = (const float*)d_in[5];  const float* bB  = (const float*)d_in[6];
    const float* WC  = (const float*)d_in[7];  const float* bC  = (const float*)d_in[8];
    const float* WD  = (const float*)d_in[9];  const float* bD  = (const float*)d_in[10];
    const float* WE  = (const float*)d_in[11]; const float* bE  = (const float*)d_in[12];
    const float* g_x = (const float*)d_in[13]; const float* b_x = (const float*)d_in[14];
    const float* g_e = (const float*)d_in[15]; const float* b_e = (const float*)d_in[16];
    const float* g_n1= (const float*)d_in[17]; const float* b_n1= (const float*)d_in[18];
    const float* W1  = (const float*)d_in[19]; const float* b1  = (const float*)d_in[20];
    const float* W2  = (const float*)d_in[21]; const float* b2  = (const float*)d_in[22];
    const float* g_n2= (const float*)d_in[23]; const float* b_n2= (const float*)d_in[24];

    const int N = in_sizes[0]/64;
    const int E = in_sizes[2]/64;

    // ---- workspace layout ----
    float* ws   = (float*)d_ws;
    float* AxB  = ws;                        // [N,64]; reused as xf
    float* Bx   = AxB + (size_t)N*64;        // [N,64]; reused as yv
    float* Dx   = Bx  + (size_t)N*64;        // [N,64] ┐ reused as h1 [N,128]
    float* Ex   = Dx  + (size_t)N*64;        // [N,64] ┘
    float* xt   = Ex  + (size_t)N*64;        // [N,64]
    float* st   = xt  + (size_t)N*64;        // 512 floats
    float* part = st + 512;                  // 2048*128 floats
    int*   deg    = (int*)(part + 2048*128);
    int*   rowptr = deg + N;
    int*   cursor = rowptr + (N+1);
    int*   bsumB  = cursor + N;
    int*   boffB  = bsumB + 256;
    int*   csr_eid= boffB + 256;
    int*   csr_col= csr_eid + E;

    float* xf = AxB;
    float* yv = Bx;
    float* h1 = Dx;

    float* st_e  = st;
    float* st_xt = st + 128;
    float* st_xf = st + 256;
    float* st_y  = st + 384;

    float* outx = (float*)d_out;             // [N,64]
    float* eij  = outx + (size_t)N*64;       // [E,64]: Ce -> e_ij -> e_final in-place

    const int nbN    = (N+TPB-1)/TPB;
    const int nbE    = (E+TPB-1)/TPB;
    const int nbN16  = (N*16+TPB-1)/TPB;
    const long e16   = (long)E*16;
    const int nbE16  = (int)((e16+TPB-1)/TPB);
    const int nchunk = (N+TPB-1)/TPB;

    hipMemsetAsync(deg, 0, (size_t)N*sizeof(int), stream);
    hipMemsetAsync(st,  0, 512*sizeof(float),     stream);

    k_rowgemm<<<nbN, TPB, 0, stream>>>(x,  WA, bA, AxB, N);
    k_rowgemm<<<nbN, TPB, 0, stream>>>(x,  WB, bB, Bx,  N);
    k_rowgemm<<<nbN, TPB, 0, stream>>>(x,  WD, bD, Dx,  N);
    k_rowgemm<<<nbN, TPB, 0, stream>>>(x,  WE, bE, Ex,  N);
    k_rowgemm<<<nbE, TPB, 0, stream>>>(ea, WC, bC, eij, E);

    k_hist <<<2048, TPB, 0, stream>>>(ei, deg, E);
    k_scanA<<<nchunk, TPB, 0, stream>>>(deg, rowptr, bsumB, N);
    k_scanB<<<1, TPB, 0, stream>>>(bsumB, boffB, nchunk);
    k_scanC<<<nchunk, TPB, 0, stream>>>(rowptr, cursor, boffB, N, E);
    k_pos  <<<2048, TPB, 0, stream>>>(ei, cursor, csr_eid, csr_col, E);

    k_edge2<<<nbE16, TPB, 0, stream>>>(ei, Dx, Ex, eij, E);

    k_part<<<2048, TPB, 0, stream>>>(eij, part, (long)E);
    k_red2<<<2048/RCH, TPB, 0, stream>>>(part, st_e, 2048);

    k_aggr<<<(N+3)/4, TPB, 0, stream>>>(AxB, Bx, eij, csr_eid, csr_col, rowptr, xt, N);

    k_part<<<512, TPB, 0, stream>>>(xt, part, (long)N);
    k_red2<<<512/RCH, TPB, 0, stream>>>(part, st_xt, 512);

    k_xupdate<<<nbN16, TPB, 0, stream>>>(x, xt, st_xt, g_x, b_x, xf, N);

    k_part<<<512, TPB, 0, stream>>>(xf, part, (long)N);
    k_red2<<<512/RCH, TPB, 0, stream>>>(part, st_xf, 512);

    k_ffn1<<<dim3(nbN,2), TPB, 0, stream>>>(xf, st_xf, g_n1, b_n1, W1, b1, h1, N);
    k_ffn2<<<dim3(nbN,2), TPB, 0, stream>>>(h1, xf, W2, b2, yv, N);

    k_part<<<512, TPB, 0, stream>>>(yv, part, (long)N);
    k_red2<<<512/RCH, TPB, 0, stream>>>(part, st_y, 512);

    k_bnout <<<nbN16, TPB, 0, stream>>>(yv, st_y, g_n2, b_n2, outx, N);
    k_efinal<<<nbE16, TPB, 0, stream>>>(ea, eij, st_e, g_e, b_e, E);
}